// Round 15
// baseline (368.421 us; speedup 1.0000x reference)
//
#include <hip/hip_runtime.h>
#include <hip/hip_fp16.h>
#include <cstdint>
#include <cstddef>

#define GLOBAL_AS __attribute__((address_space(1)))
#define LDS_AS    __attribute__((address_space(3)))

typedef __attribute__((ext_vector_type(8))) _Float16 f16x8;
typedef __attribute__((ext_vector_type(4))) float    f32x4;

__device__ __forceinline__ void gload_lds16(const void* g, void* l) {
    __builtin_amdgcn_global_load_lds((const GLOBAL_AS void*)g,
                                     (LDS_AS void*)l, 16, 0, 0);
}

// fp16 quantizer == reference fp_quantize_ste(exp=5, sig=10): RNE + saturate.
__device__ __forceinline__ __half qcvt(float x) {
    x = fminf(fmaxf(x, -65504.f), 65504.f);
    return __float2half(x);   // v_cvt_f16_f32: RNE, subnormals handled
}

// Fused quantization of x and w (both f32 -> f16), one launch, grid-stride.
__global__ void quant_xw_f32_to_f16(const float* __restrict__ xin, int x4,
                                    const float* __restrict__ win, int w4,
                                    __half* __restrict__ xout,
                                    __half* __restrict__ wout) {
    const int stride = gridDim.x * blockDim.x;
    const int tot = x4 + w4;
    for (int i = blockIdx.x * blockDim.x + threadIdx.x; i < tot; i += stride) {
        const bool isx = (i < x4);
        const int  j   = isx ? i : i - x4;
        const float4 f = reinterpret_cast<const float4*>(isx ? xin : win)[j];
        union { __half h[4]; uint2 u; } p;
        p.h[0] = qcvt(f.x);
        p.h[1] = qcvt(f.y);
        p.h[2] = qcvt(f.z);
        p.h[3] = qcvt(f.w);
        reinterpret_cast<uint2*>(isx ? xout : wout)[j] = p.u;
    }
}

// ---------------------------------------------------------------------------
// ROUND 15: R14 geometry (128x128 tile, BK=64, 4 waves 2Mx2N each 64x64,
// 64 KiB LDS -> 2 blocks/CU) with the wave<->slab mapping FIXED:
//
// B slabs are split BY FRAGMENT INDEX n, not by row range:
//   B01-slab = W-rows  0..31 u 64..95   (n in {0,1} for BOTH wc groups)
//            = region bytes 0..4095 u 8192..12287
//   B23-slab = W-rows 32..63 u 96..127  (n in {2,3} for both wc)
//            = region bytes 4096..8191 u 12288..16383
// Fragment (wc,n,kk) byte = wc*8192 + n*2048 + kk*1024: n<=1 -> B01-slab,
// n>=2 -> B23-slab (checked for both wc). R14's row-range split broke this:
// wave wc=1's P0 fragments lived in the unconfirmed B23 slab.
// Also fixed: tail tile nt-2 gets vmcnt(8) before its first barrier
// (retires B23(nt-2), the oldest 2 of 10 outstanding) — latent race.
//
// LDS: lds[buf][op A=0/B=1][16 KiB region], subtile si=(row>>4)*2+(cb>>6),
// in-subtile = ((row&15)*64+(cb&63)) ^ (((row>>3)&1)<<5) [st_16x32 swizzle].
// Staging per 4KiB call: dest = slab_byte + tid*16 (linear); source
//   row = 32*call + (tid>>7)*16 + (wbyte>>6), cb = ((tid>>6)&1)*64+(wbyte&63),
//   wbyte = (tid&63)*16 ^ (((tid>>5)&1)<<5)   [verified fwd/inv, tid 40/65].
//
// Schedule per K-tile, 2 phases:
//  P0: reads A(8) + B n0,n1 (4); stages B23(t+1)->nxt [2]; W3/2/1/0 + MMAs;
//      vmcnt(8) retires B23(t) (oldest 2 of 10); barrier.
//  P1: reads B n2,n3 (4); stages A(t+2)+B01(t+2)->cur [6]; W3/2/1/0 + MMAs;
//      vmcnt(8) retires A(t+1)+B01(t+1) (oldest 6 of 14); barrier.
// Ledger: A(t),B01(t) staged @(t-2).P1, confirmed @(t-1).P1 VM8;
//         B23(t) staged @(t-1).P0, confirmed @t.P0 VM8 (read only in P1). ✓
// ---------------------------------------------------------------------------
__global__ __launch_bounds__(256, 2) void gemm_f16_128sq(
    const __half* __restrict__ A, const __half* __restrict__ B,
    const float* __restrict__ bias, float* __restrict__ C,
    int M, int N, int K)
{
    __shared__ __align__(16) __half lds[2][2][8192];   // 64 KiB

    const int tid  = threadIdx.x;
    const int lane = tid & 63;
    const int wid  = tid >> 6;     // 4 waves
    const int wr   = wid >> 1;     // 0..1 (M)
    const int wc   = wid & 1;      // 0..1 (N)
    const int fr   = lane & 15;
    const int fq   = lane >> 4;

    // bijective XCD swizzle (m204)
    const int nwg = gridDim.x;
    const int qq = nwg >> 3, rr = nwg & 7;
    const int xcd = blockIdx.x & 7, idx = blockIdx.x >> 3;
    const int wgid = (xcd < rr ? xcd * (qq + 1)
                               : rr * (qq + 1) + (xcd - rr) * qq) + idx;
    const int nbn = N >> 7;
    const int tile_m = (wgid / nbn) << 7;
    const int tile_n = (wgid % nbn) << 7;

    // ---- staging source coords (inverse of swizzle, per thread) ----
    const int wbyte = (lane * 16) ^ (((lane >> 5) & 1) << 5);
    const int srow  = ((tid >> 7) << 4) + (wbyte >> 6);   // 0..31
    const int scb   = (((tid >> 6) & 1) << 6) + (wbyte & 63);
    const char* gA0 = (const char*)A + (size_t)(tile_m + srow) * K * 2 + scb;
    const char* gB0 = (const char*)B + (size_t)(tile_n + srow) * K * 2 + scb;
    const size_t cstep = (size_t)32 * K * 2;    // +32 rows per call
    const int ldst = tid * 16;                  // linear LDS dest byte

    // ---- fragment-read LDS byte addresses (st_16x32 swizzled) ----
    const int woff = (fr * 64 + fq * 16) ^ (((fr >> 3) & 1) << 5);
    const uint32_t lds0 = (uint32_t)(size_t)(LDS_AS const char*)&lds[0][0][0];
    const uint32_t aBase = lds0 + (uint32_t)(wr * 8192 + woff);
    const uint32_t bBase = lds0 + 16384u + (uint32_t)(wc * 8192 + woff);
    // A frag (m,kk): aBase + buf*32768 + m*2048 + kk*1024
    // B frag (n,kk): bBase + buf*32768 + n*2048 + kk*1024

    f32x4 acc[4][4];
#pragma unroll
    for (int m = 0; m < 4; ++m)
#pragma unroll
        for (int n = 0; n < 4; ++n)
            acc[m][n] = (f32x4){0.f, 0.f, 0.f, 0.f};

    f16x8 af[4][2];    // A fragments [m][kk]
    f16x8 bf[4][2];    // B fragments [n][kk]

#define STAGE_A(bufi, kt) do {                                             \
        char* l_ = (char*)(&lds[bufi][0][0]) + ldst;                       \
        const char* g_ = gA0 + (size_t)(kt) * 128;                         \
        gload_lds16(g_,             l_);                                   \
        gload_lds16(g_ + cstep,     l_ + 4096);                            \
        gload_lds16(g_ + 2 * cstep, l_ + 8192);                            \
        gload_lds16(g_ + 3 * cstep, l_ + 12288);                           \
    } while (0)

// B01-slab: W-rows 0..31 (si 0..3) and 64..95 (si 8..11) -> n in {0,1}
#define STAGE_B01(bufi, kt) do {                                           \
        char* l_ = (char*)(&lds[bufi][1][0]) + ldst;                       \
        const char* g_ = gB0 + (size_t)(kt) * 128;                         \
        gload_lds16(g_,             l_);                                   \
        gload_lds16(g_ + 2 * cstep, l_ + 8192);                            \
    } while (0)

// B23-slab: W-rows 32..63 (si 4..7) and 96..127 (si 12..15) -> n in {2,3}
#define STAGE_B23(bufi, kt) do {                                           \
        char* l_ = (char*)(&lds[bufi][1][0]) + ldst;                       \
        const char* g_ = gB0 + (size_t)(kt) * 128;                         \
        gload_lds16(g_ + cstep,     l_ + 4096);                            \
        gload_lds16(g_ + 3 * cstep, l_ + 12288);                           \
    } while (0)

// inline-asm ds_read_b128, base VGPR + constant offset via %c
#define DSR(dst, base, OFF)                                                \
    asm volatile("ds_read_b128 %0, %1 offset:%c2"                          \
                 : "=v"(dst) : "v"(base), "i"(OFF))

// 8 A reads: m0k0,m0k1,...,m3k1
#define LDGA(BUFOFF) do {                                                  \
        DSR(af[0][0], aBase, (BUFOFF) + 0);                                \
        DSR(af[0][1], aBase, (BUFOFF) + 1024);                             \
        DSR(af[1][0], aBase, (BUFOFF) + 2048);                             \
        DSR(af[1][1], aBase, (BUFOFF) + 3072);                             \
        DSR(af[2][0], aBase, (BUFOFF) + 4096);                             \
        DSR(af[2][1], aBase, (BUFOFF) + 5120);                             \
        DSR(af[3][0], aBase, (BUFOFF) + 6144);                             \
        DSR(af[3][1], aBase, (BUFOFF) + 7168);                             \
    } while (0)

// 4 B reads at n-block NB0, NB0+1 (n0k0,n0k1,n1k0,n1k1 order)
#define LDGB2(NB0, BUFOFF) do {                                            \
        DSR(bf[(NB0)][0],     bBase, (BUFOFF) + (NB0)*2048 + 0);           \
        DSR(bf[(NB0)][1],     bBase, (BUFOFF) + (NB0)*2048 + 1024);        \
        DSR(bf[(NB0)+1][0],   bBase, (BUFOFF) + (NB0)*2048 + 2048);        \
        DSR(bf[(NB0)+1][1],   bBase, (BUFOFF) + (NB0)*2048 + 3072);        \
    } while (0)

#define MMA_NK(NN, KK)                                                     \
    __builtin_amdgcn_s_setprio(1);                                         \
    acc[0][NN] = __builtin_amdgcn_mfma_f32_16x16x32_f16(                   \
        af[0][KK], bf[NN][KK], acc[0][NN], 0, 0, 0);                       \
    acc[1][NN] = __builtin_amdgcn_mfma_f32_16x16x32_f16(                   \
        af[1][KK], bf[NN][KK], acc[1][NN], 0, 0, 0);                       \
    acc[2][NN] = __builtin_amdgcn_mfma_f32_16x16x32_f16(                   \
        af[2][KK], bf[NN][KK], acc[2][NN], 0, 0, 0);                       \
    acc[3][NN] = __builtin_amdgcn_mfma_f32_16x16x32_f16(                   \
        af[3][KK], bf[NN][KK], acc[3][NN], 0, 0, 0);                       \
    __builtin_amdgcn_s_setprio(0);

// counted lgkm wait + scheduler fence (rule #18)
#define WAITL(NLIT)                                                        \
    asm volatile("s_waitcnt lgkmcnt(" NLIT ")");                           \
    __builtin_amdgcn_sched_barrier(0)

#define VM8()  asm volatile("s_waitcnt vmcnt(8)")
#define BARS() __builtin_amdgcn_s_barrier()

#define TILE(cur, nxt, kt)                                                 \
    /* P0: MFMA n0-1; reads A(8)+B01(4); stage B23(t+1)->nxt */            \
    LDGA((cur) * 32768);                                                   \
    LDGB2(0, (cur) * 32768);                                               \
    STAGE_B23(nxt, (kt) + 1);                                              \
    WAITL("3"); MMA_NK(0, 0);                                              \
    WAITL("2"); MMA_NK(0, 1);                                              \
    WAITL("1"); MMA_NK(1, 0);                                              \
    WAITL("0"); MMA_NK(1, 1);                                              \
    VM8(); BARS();                                                         \
    /* P1: MFMA n2-3; reads B23(4); stage A(t+2)+B01(t+2)->cur */          \
    LDGB2(2, (cur) * 32768);                                               \
    STAGE_A(cur, (kt) + 2);                                                \
    STAGE_B01(cur, (kt) + 2);                                              \
    WAITL("3"); MMA_NK(2, 0);                                              \
    WAITL("2"); MMA_NK(2, 1);                                              \
    WAITL("1"); MMA_NK(3, 0);                                              \
    WAITL("0"); MMA_NK(3, 1);                                              \
    VM8(); BARS();

    // ---- prologue: tile0 full (8 ops) + tile1 A,B01 (6 ops) ----
    STAGE_A(0, 0); STAGE_B01(0, 0); STAGE_B23(0, 0);
    STAGE_A(1, 1); STAGE_B01(1, 1);
    asm volatile("s_waitcnt vmcnt(6)");   // tile0 retired; tile1's 6 in flight
    BARS();

    const int nt = K >> 6;              // even, >= 4 (guarded by launcher)
    for (int kt = 0; kt + 3 < nt; kt += 2) {
        TILE(0, 1, kt);
        TILE(1, 0, kt + 1);
    }

    // ---- tile nt-2 (buf0): stage only B23(nt-1); vmcnt(8) retires B23(t) --
    LDGA(0);
    LDGB2(0, 0);
    STAGE_B23(1, nt - 1);
    WAITL("3"); MMA_NK(0, 0);
    WAITL("2"); MMA_NK(0, 1);
    WAITL("1"); MMA_NK(1, 0);
    WAITL("0"); MMA_NK(1, 1);
    VM8(); BARS();
    LDGB2(2, 0);
    WAITL("3"); MMA_NK(2, 0);
    WAITL("2"); MMA_NK(2, 1);
    WAITL("1"); MMA_NK(3, 0);
    WAITL("0"); MMA_NK(3, 1);
    asm volatile("s_waitcnt vmcnt(0)");
    BARS();

    // ---- tile nt-1 (buf1): pure compute ----
    LDGA(32768);
    LDGB2(0, 32768);
    WAITL("3"); MMA_NK(0, 0);
    WAITL("2"); MMA_NK(0, 1);
    WAITL("1"); MMA_NK(1, 0);
    WAITL("0"); MMA_NK(1, 1);
    LDGB2(2, 32768);
    WAITL("3"); MMA_NK(2, 0);
    WAITL("2"); MMA_NK(2, 1);
    WAITL("1"); MMA_NK(3, 0);
    WAITL("0"); MMA_NK(3, 1);

    // ---- epilogue: C/D layout col=lane&15, row=fq*4+reg (m89-verified) ----
    float bv[4];
#pragma unroll
    for (int n = 0; n < 4; ++n)
        bv[n] = __half2float(qcvt(bias[tile_n + wc * 64 + n * 16 + fr]));

#pragma unroll
    for (int m = 0; m < 4; ++m)
#pragma unroll
        for (int n = 0; n < 4; ++n) {
            const int col  = tile_n + wc * 64 + n * 16 + fr;
            const int rowb = tile_m + wr * 64 + m * 16 + fq * 4;
#pragma unroll
            for (int r = 0; r < 4; ++r)
                C[(size_t)(rowb + r) * N + col] = acc[m][n][r] + bv[n];
        }

#undef STAGE_A
#undef STAGE_B01
#undef STAGE_B23
#undef DSR
#undef LDGA
#undef LDGB2
#undef MMA_NK
#undef WAITL
#undef VM8
#undef BARS
#undef TILE
}

// ---------------------------------------------------------------------------
// Insurance fallback (shape or ws mismatch): fused naive, slow but correct.
// ---------------------------------------------------------------------------
__global__ void qat_gemm_naive(const float* __restrict__ A,
                               const float* __restrict__ B,
                               const float* __restrict__ bias,
                               float* __restrict__ C, int M, int N, int K) {
    const int col = blockIdx.x * blockDim.x + threadIdx.x;
    const int row = blockIdx.y;
    if (col >= N || row >= M) return;
    float s = 0.f;
    for (int k = 0; k < K; ++k) {
        float a = __half2float(qcvt(A[(size_t)row * K + k]));
        float b = __half2float(qcvt(B[(size_t)col * K + k]));
        s += a * b;
    }
    C[(size_t)row * N + col] = s + __half2float(qcvt(bias[col]));
}

// ---------------------------------------------------------------------------
extern "C" void kernel_launch(void* const* d_in, const int* in_sizes, int n_in,
                              void* d_out, int out_size, void* d_ws,
                              size_t ws_size, hipStream_t stream) {
    const float* x = (const float*)d_in[0];
    const float* w = (const float*)d_in[1];
    const float* b = (const float*)d_in[2];
    float* out = (float*)d_out;

    const int xn = in_sizes[0];     // M*K
    const int wn = in_sizes[1];     // N*K
    const int N  = in_sizes[2];     // 4096
    const int K  = wn / N;          // 4096
    const int M  = xn / K;          // 8192

    const size_t need = (size_t)(xn + wn) * sizeof(__half);
    const bool ok = (M % 128 == 0) && (N % 128 == 0) &&
                    (K % 128 == 0) && (K >= 256);

    if (ws_size >= need && ok) {
        __half* xq = (__half*)d_ws;
        __half* wq = xq + xn;

        const int x4 = xn / 4, w4 = wn / 4;
        int blk = ((x4 + w4) + 255) / 256; if (blk > 2048) blk = 2048;
        quant_xw_f32_to_f16<<<blk, 256, 0, stream>>>(x, x4, w, w4, xq, wq);

        dim3 grid((M / 128) * (N / 128));
        gemm_f16_128sq<<<grid, 256, 0, stream>>>(xq, wq, b, out, M, N, K);
    } else {
        dim3 grid((N + 255) / 256, M);
        qat_gemm_naive<<<grid, 256, 0, stream>>>(x, w, b, out, M, N, K);
    }
}